// Round 5
// baseline (534.228 us; speedup 1.0000x reference)
//
#include <hip/hip_runtime.h>

// out = A @ x, A sparse COO (rows, cols, edge_vals), x [N,64] f32.
// Counting-sort edges into 8-row buckets, with each bucket split into NG=8
// XCD-group segments (group = blockIdx&7 ~ XCD): a segment's pair-lines are
// written by ONE XCD only -> full 64B line fills -> write combining works
// (previous rounds: WRITE_SIZE == E*64B from inter-XCD partial-line flushes).
// Reduce: one block per bucket, waves partition edges (i%4==w), accumulate
// into LDS f32 atomics s_acc[r3*64+lane] (conflict-free banks), single
// coalesced store per row. No global output atomics anywhere.

#define D_FEAT 64
#define RPB 8                  // rows per bucket (3 bits in pair.x[27:25])
#define NG 8                   // scatter groups ~ XCDs

// ---------------- fallback (round-1 kernel) ----------------
__global__ void spmv_coo_kernel(const float* __restrict__ x,
                                const int* __restrict__ rows,
                                const int* __restrict__ cols,
                                const float* __restrict__ ev,
                                float* __restrict__ out,
                                int n_edges) {
    const int lane = threadIdx.x & 63;
    const int wave_global = blockIdx.x * (blockDim.x >> 6) + (threadIdx.x >> 6);
    const int n_waves = gridDim.x * (blockDim.x >> 6);
    for (int e = wave_global; e < n_edges; e += n_waves) {
        atomicAdd(&out[rows[e] * D_FEAT + lane], ev[e] * x[cols[e] * D_FEAT + lane]);
    }
}

// ---------------- phase 1: (bucket,group) histogram ----------------
__global__ void hist_kernel(const int* __restrict__ rows, int* __restrict__ counts,
                            int n_edges) {
    const int g = blockIdx.x & (NG - 1);
    int gid = blockIdx.x * blockDim.x + threadIdx.x;
    int stride = gridDim.x * blockDim.x;
    for (int e = gid; e < n_edges; e += stride)
        atomicAdd(&counts[(rows[e] >> 3) * NG + g], 1);
}

// ---------------- phase 2: scan over NC = n_buckets*NG counts ----------------
__global__ void scan_block_kernel(const int* __restrict__ counts,
                                  int* __restrict__ offsets,
                                  int* __restrict__ blocksums, int n) {
    __shared__ int s[256];
    int t = threadIdx.x;
    int gid = blockIdx.x * 256 + t;
    int val = (gid < n) ? counts[gid] : 0;
    s[t] = val;
    __syncthreads();
    for (int off = 1; off < 256; off <<= 1) {
        int tmp = (t >= off) ? s[t - off] : 0;
        __syncthreads();
        s[t] += tmp;
        __syncthreads();
    }
    if (gid < n) offsets[gid] = s[t] - val;   // exclusive within block
    if (t == 0) blocksums[blockIdx.x] = s[255];
}

__global__ void scan_tops_kernel(int* __restrict__ blocksums, int nblk) {
    __shared__ int s[512];
    int t = threadIdx.x;
    int val = (t < nblk) ? blocksums[t] : 0;
    s[t] = val;
    __syncthreads();
    for (int off = 1; off < 512; off <<= 1) {
        int tmp = (t >= off) ? s[t - off] : 0;
        __syncthreads();
        s[t] += tmp;
        __syncthreads();
    }
    if (t < nblk) blocksums[t] = s[t] - val;  // exclusive
}

// 2c: add block prefix; write cursor TRANSPOSED (group-major) so each
// group's cursor lines are touched by one XCD only; offsets[n] = E.
__global__ void scan_add_kernel(int* __restrict__ offsets,
                                const int* __restrict__ blocksums,
                                int* __restrict__ cursor,
                                int n, int n_buckets, int n_edges) {
    int gid = blockIdx.x * 256 + threadIdx.x;
    if (gid < n) {
        int v = offsets[gid] + blocksums[gid >> 8];
        offsets[gid] = v;
        cursor[(gid & (NG - 1)) * n_buckets + (gid >> 3)] = v;  // [g][bucket]
    }
    if (gid == 0) offsets[n] = n_edges;
}

// ---------------- phase 3: scatter into (bucket,group)-sorted order --------
__global__ void scatter_kernel(const int* __restrict__ rows,
                               const int* __restrict__ cols,
                               const float* __restrict__ ev,
                               int* __restrict__ cursor,
                               uint2* __restrict__ pairs,
                               int n_buckets, int n_edges) {
    const int g = blockIdx.x & (NG - 1);
    int gid = blockIdx.x * blockDim.x + threadIdx.x;
    int stride = gridDim.x * blockDim.x;
    for (int e = gid; e < n_edges; e += stride) {
        int r = rows[e];
        int pos = atomicAdd(&cursor[g * n_buckets + (r >> 3)], 1);
        uint2 p;
        p.x = (unsigned)cols[e] | ((unsigned)(r & 7) << 25);  // col < 2^25
        p.y = __float_as_uint(ev[e]);
        pairs[pos] = p;
    }
}

// ---------------- phase 4: per-bucket reduction ----------------
// Bucket b's edges are contiguous: [offsets[b*8], offsets[(b+1)*8]).
// Wave w processes every 4th edge; LDS f32 atomic accumulate per (row,lane).
__global__ void __launch_bounds__(256) bucket_reduce_kernel(
        const float* __restrict__ x,
        const int* __restrict__ offsets,
        const uint2* __restrict__ pairs,
        float* __restrict__ out, int n_rows) {
    __shared__ float s_acc[RPB * D_FEAT];     // 2 KB
    const int tid = threadIdx.x;
    const int lane = tid & 63;
    const int w = tid >> 6;                   // 0..3
    const int b = blockIdx.x;

    s_acc[tid] = 0.0f;
    s_acc[tid + 256] = 0.0f;
    __syncthreads();

    const int s = offsets[b * NG];
    const int e = offsets[(b + 1) * NG];
    for (int i = s + w; i < e; i += 4) {
        const uint2 p = pairs[i];             // wave-uniform broadcast load
        const int r3 = (int)(p.x >> 25);
        const int c  = (int)(p.x & 0x01FFFFFFu);
        const float m = __uint_as_float(p.y) * x[c * D_FEAT + lane];
        atomicAdd(&s_acc[r3 * D_FEAT + lane], m);   // ds_add_f32, bank = lane%32
    }
    __syncthreads();

    const int row0 = b * RPB + w * 2;
    if (row0 < n_rows)
        out[row0 * D_FEAT + lane] = s_acc[(w * 2) * D_FEAT + lane];
    if (row0 + 1 < n_rows)
        out[(row0 + 1) * D_FEAT + lane] = s_acc[(w * 2 + 1) * D_FEAT + lane];
}

extern "C" void kernel_launch(void* const* d_in, const int* in_sizes, int n_in,
                              void* d_out, int out_size, void* d_ws, size_t ws_size,
                              hipStream_t stream) {
    const float* x    = (const float*)d_in[1];
    const int*   rows = (const int*)d_in[2];
    const int*   cols = (const int*)d_in[3];
    const float* ev   = (const float*)d_in[4];
    float* out = (float*)d_out;
    const int n_edges = in_sizes[3];
    const int n_rows  = out_size / D_FEAT;
    const int n_buckets = (n_rows + RPB - 1) / RPB;   // 12,500
    const int nc = n_buckets * NG;                     // 100,000 counts

    // workspace layout (bytes)
    size_t off_counts  = 0;
    size_t off_offsets = off_counts + (size_t)nc * 4;
    size_t off_cursor  = off_offsets + ((size_t)nc + 2) * 4;
    const int nblk = (nc + 255) / 256;                 // 391 (<=512)
    size_t off_bsums   = off_cursor + (size_t)nc * 4;
    size_t off_pairs   = (off_bsums + (size_t)nblk * 4 + 7) & ~(size_t)7;
    size_t need = off_pairs + (size_t)n_edges * 8;

    if (ws_size < need || nblk > 512) {
        hipMemsetAsync(d_out, 0, (size_t)out_size * sizeof(float), stream);
        spmv_coo_kernel<<<4096, 256, 0, stream>>>(x, rows, cols, ev, out, n_edges);
        return;
    }

    char* ws = (char*)d_ws;
    int*   counts  = (int*)(ws + off_counts);
    int*   offsets = (int*)(ws + off_offsets);
    int*   cursor  = (int*)(ws + off_cursor);
    int*   bsums   = (int*)(ws + off_bsums);
    uint2* pairs   = (uint2*)(ws + off_pairs);

    hipMemsetAsync(counts, 0, (size_t)nc * 4, stream);

    const int block = 256;
    const int gs_grid = 2048;   // multiple of NG

    hist_kernel<<<gs_grid, block, 0, stream>>>(rows, counts, n_edges);
    scan_block_kernel<<<nblk, 256, 0, stream>>>(counts, offsets, bsums, nc);
    scan_tops_kernel<<<1, 512, 0, stream>>>(bsums, nblk);
    scan_add_kernel<<<nblk, 256, 0, stream>>>(offsets, bsums, cursor, nc, n_buckets, n_edges);
    scatter_kernel<<<gs_grid, block, 0, stream>>>(rows, cols, ev, cursor, pairs, n_buckets, n_edges);

    bucket_reduce_kernel<<<n_buckets, 256, 0, stream>>>(x, offsets, pairs, out, n_rows);
}